// Round 1
// baseline (213.932 us; speedup 1.0000x reference)
//
#include <hip/hip_runtime.h>
#include <hip/hip_bf16.h>
#include <math.h>

#define BS   128
#define NT   25
#define CREC 107
#define CLOC 25
#define QN   1024      // H*W = 32*32 queries = columns m of the transposed cost
#define INFD 1e18

// focal-loss matcher cost: pos - neg for sigmoid prob p, f32 exactly as reference
__device__ __forceinline__ float focal_cost_f(float x) {
    float p   = 1.0f / (1.0f + expf(-x));
    float neg = 0.75f * p * p * (-logf(1.0f - p + 1e-8f));
    float pos = 0.25f * (1.0f - p) * (1.0f - p) * (-logf(p + 1e-8f));
    return pos - neg;
}

// C[b][t][q] = 2*focal(sigmoid(rec[b, targets[b,t], q])) + focal(sigmoid(loc[b, t, q]))
__global__ void cost_kernel(const float* __restrict__ rec, const float* __restrict__ loc,
                            const int* __restrict__ targets, float* __restrict__ cost) {
    int bid = blockIdx.x;            // b*NT + t
    int b = bid / NT, t = bid % NT;
    int tc = targets[b * NT + t];
    const float* rrow = rec + ((size_t)b * CREC + tc) * QN;
    const float* lrow = loc + ((size_t)b * CLOC + t) * QN;
    float* crow = cost + (size_t)bid * QN;
    for (int q = threadIdx.x; q < QN; q += blockDim.x) {
        crow[q] = 2.0f * focal_cost_f(rrow[q]) + focal_cost_f(lrow[q]);
    }
}

// One block per batch: Jonker-Volgenant LSA on the 25x1024 (transposed) cost,
// f64 potentials to match scipy/np float64 semantics, then fused CE losses.
__global__ __launch_bounds__(256)
void hungarian_loss_kernel(const float* __restrict__ cost,
                           const float* __restrict__ rec, const float* __restrict__ loc,
                           const int* __restrict__ targets, float* __restrict__ out) {
    const int b   = blockIdx.x;
    const int tid = threadIdx.x;

    __shared__ double u_s[NT + 2];
    __shared__ double v_s[QN + 8];
    __shared__ double minv_s[QN + 8];
    __shared__ int    way_s[QN + 8];
    __shared__ int    p_s[QN + 8];
    __shared__ unsigned char used_s[QN + 8];
    __shared__ double redv[256];
    __shared__ int    redi[256];
    __shared__ int    pairq[NT];

    for (int j = tid; j <= QN; j += 256) { v_s[j] = 0.0; p_s[j] = 0; way_s[j] = 0; }
    if (tid <= NT) u_s[tid] = 0.0;
    __syncthreads();

    const float* cbase = cost ? (cost + (size_t)b * NT * QN) : nullptr;

    for (int i = 1; i <= NT; ++i) {
        for (int j = tid; j <= QN; j += 256) { minv_s[j] = INFD; used_s[j] = 0; }
        if (tid == 0) p_s[0] = i;
        __syncthreads();

        int j0 = 0;
        for (int iter = 0; iter < QN + 2; ++iter) {
            if (tid == 0) used_s[j0] = 1;
            __syncthreads();
            const int i0   = p_s[j0];
            const double ui0 = u_s[i0];
            const int trow = i0 - 1;
            const float* crow = nullptr;
            const float* rrow = nullptr;
            const float* lrow = nullptr;
            if (cbase) {
                crow = cbase + (size_t)trow * QN;
            } else {
                int tc = targets[b * NT + trow];
                rrow = rec + ((size_t)b * CREC + tc) * QN;
                lrow = loc + ((size_t)b * CLOC + trow) * QN;
            }

            // scan free columns: relax minv/way, track local argmin (first-index ties)
            double bestv = INFD; int besti = 0;
            for (int j = tid + 1; j <= QN; j += 256) {
                if (!used_s[j]) {
                    float cf = cbase ? crow[j - 1]
                                     : (2.0f * focal_cost_f(rrow[j - 1]) + focal_cost_f(lrow[j - 1]));
                    double cur = (double)cf - ui0 - v_s[j];
                    if (cur < minv_s[j]) { minv_s[j] = cur; way_s[j] = j0; }
                    double mv = minv_s[j];
                    if (mv < bestv || (mv == bestv && j < besti)) { bestv = mv; besti = j; }
                }
            }
            redv[tid] = bestv; redi[tid] = besti;
            __syncthreads();
            for (int s = 128; s >= 1; s >>= 1) {
                if (tid < s) {
                    double bv = redv[tid + s]; int bi = redi[tid + s];
                    if (bv < redv[tid] || (bv == redv[tid] && bi < redi[tid])) {
                        redv[tid] = bv; redi[tid] = bi;
                    }
                }
                __syncthreads();
            }
            const double delta = redv[0];
            const int j1 = redi[0];

            // u[p[used]] += delta; v[used] -= delta; minv[free] -= delta
            for (int j = tid; j <= QN; j += 256) {
                if (used_s[j]) { u_s[p_s[j]] += delta; v_s[j] -= delta; }
                else           { minv_s[j] -= delta; }
            }
            __syncthreads();
            j0 = j1;
            if (p_s[j0] == 0) break;
        }
        // augment along the alternating path (sequential, short)
        if (tid == 0) {
            int jj = j0;
            while (jj != 0) { int jn = way_s[jj]; p_s[jj] = p_s[jn]; jj = jn; }
        }
        __syncthreads();
    }

    // collect matched pairs: column j assigned to target row p_s[j]-1
    for (int j = tid + 1; j <= QN; j += 256)
        if (p_s[j] > 0) pairq[p_s[j] - 1] = j - 1;
    __syncthreads();

    // fused CE losses; mean is permutation-invariant so no sorting needed
    const int wave = tid >> 6, lane = tid & 63;
    float recsum = 0.0f, locsum = 0.0f;
    for (int t = wave; t < NT; t += 4) {
        const int q = pairq[t];

        // rec CE over 107 classes at query q
        const float* rb = rec + (size_t)b * CREC * QN + q;
        float x0 = (lane < CREC)      ? rb[(size_t)lane * QN]        : -1e30f;
        float x1 = (lane + 64 < CREC) ? rb[(size_t)(lane + 64) * QN] : -1e30f;
        float mx = fmaxf(x0, x1);
        for (int off = 32; off; off >>= 1) mx = fmaxf(mx, __shfl_xor(mx, off));
        float e = 0.0f;
        if (lane < CREC)      e += expf(x0 - mx);
        if (lane + 64 < CREC) e += expf(x1 - mx);
        for (int off = 32; off; off >>= 1) e += __shfl_xor(e, off);
        float lse = mx + logf(e);
        int lab = targets[b * NT + t];
        recsum += lse - rb[(size_t)lab * QN];

        // loc CE over 25 classes at query q, label = t
        const float* lb = loc + (size_t)b * CLOC * QN + q;
        float y = (lane < CLOC) ? lb[(size_t)lane * QN] : -1e30f;
        float my = y;
        for (int off = 32; off; off >>= 1) my = fmaxf(my, __shfl_xor(my, off));
        float ey = (lane < CLOC) ? expf(y - my) : 0.0f;
        for (int off = 32; off; off >>= 1) ey += __shfl_xor(ey, off);
        float lsey = my + logf(ey);
        locsum += lsey - lb[(size_t)t * QN];
    }
    if (lane == 0) {
        atomicAdd(&out[0], recsum * (1.0f / (BS * NT)));
        atomicAdd(&out[1], locsum * (1.0f / (BS * NT)));
    }
}

extern "C" void kernel_launch(void* const* d_in, const int* in_sizes, int n_in,
                              void* d_out, int out_size, void* d_ws, size_t ws_size,
                              hipStream_t stream) {
    (void)in_sizes; (void)n_in; (void)out_size;
    const float* rec     = (const float*)d_in[0];
    const float* loc     = (const float*)d_in[1];
    const int*   targets = (const int*)d_in[2];
    float* out = (float*)d_out;

    hipMemsetAsync(d_out, 0, 2 * sizeof(float), stream);

    const size_t cost_bytes = (size_t)BS * NT * QN * sizeof(float);
    float* cost = nullptr;
    if (ws_size >= cost_bytes) {
        cost = (float*)d_ws;
        hipLaunchKernelGGL(cost_kernel, dim3(BS * NT), dim3(256), 0, stream,
                           rec, loc, targets, cost);
    }
    hipLaunchKernelGGL(hungarian_loss_kernel, dim3(BS), dim3(256), 0, stream,
                       cost, rec, loc, targets, out);
}